// Round 5
// baseline (335.492 us; speedup 1.0000x reference)
//
#include <hip/hip_runtime.h>
#include <math.h>

#define DIN    256
#define DEMB   128
#define NCB    4
#define MCODES 512
#define NCODE  2048
#define MARGIN 1.5e-4f      // >10x rigorous split-bf16 error bound (~1.3e-5)

using bf16x8 = __attribute__((ext_vector_type(8))) short;
using f32x16 = __attribute__((ext_vector_type(16))) float;

static __device__ __forceinline__ unsigned short f2bf(float f) {   // RNE f32->bf16
    unsigned u = __float_as_uint(f);
    u += 0x7FFFu + ((u >> 16) & 1u);
    return (unsigned short)(u >> 16);
}
static __device__ __forceinline__ float bf2f(unsigned short h) {
    return __uint_as_float(((unsigned)h) << 16);
}
static __device__ __forceinline__ float4 ld4(const float* p) {
    return *reinterpret_cast<const float4*>(p);
}

// ---------------------------------------------------------------------------
// Kernel 1: normalize codebook rows; emit (a) f32 copy for exact stage-B,
// (b) hi/lo bf16 split in mfma_32x32x16 A-fragment order (tile ct = 16 KB
// contiguous: [kt 0..8][hl 0..2][lane 0..64][8 shorts]).
// ---------------------------------------------------------------------------
__global__ __launch_bounds__(256) void prep_codebook(
        const float* __restrict__ cb, float* __restrict__ cbn,
        unsigned short* __restrict__ cbA) {
    const int w = threadIdx.x >> 6, lane = threadIdx.x & 63;
    const int code = blockIdx.x * 4 + w;                 // 0..2047
    const float2 v = reinterpret_cast<const float2*>(cb + (size_t)code * DEMB)[lane];
    float ss = v.x * v.x + v.y * v.y;
#pragma unroll
    for (int m = 1; m < 64; m <<= 1) ss += __shfl_xor(ss, m, 64);
    const float rn = 1.0f / sqrtf(ss);
    const float x0 = v.x * rn, x1 = v.y * rn;
    reinterpret_cast<float2*>(cbn + (size_t)code * DEMB)[lane] = make_float2(x0, x1);

    const unsigned short h0 = f2bf(x0), h1 = f2bf(x1);
    const unsigned short l0 = f2bf(x0 - bf2f(h0)), l1 = f2bf(x1 - bf2f(h1));
    const int ct = code >> 5, ci = code & 31;
    const int kt = lane >> 3, g = (lane >> 2) & 1, i = 2 * (lane & 3);
    const size_t base = ((size_t)ct * 1024 + kt * 128 + g * 32 + ci) * 8 + i;
    *reinterpret_cast<ushort2*>(cbA + base)       = make_ushort2(h0, h1);  // hi
    *reinterpret_cast<ushort2*>(cbA + base + 512) = make_ushort2(l0, l1);  // lo
}

// ---------------------------------------------------------------------------
// Kernel 2: projection x = inp @ proj (f32 VALU, register-pipelined).
// ---------------------------------------------------------------------------
__global__ __launch_bounds__(256) void project_kernel(
        const float* __restrict__ inp, const float* __restrict__ proj,
        float* __restrict__ xw, float* __restrict__ rnw) {
    const int tid = threadIdx.x, tx = tid & 31, ty = tid >> 5;
    const int rowBase = blockIdx.x * 64;

    float acc1[8][4];
#pragma unroll
    for (int i = 0; i < 8; ++i)
#pragma unroll
        for (int j = 0; j < 4; ++j) acc1[i][j] = 0.0f;

    const float* inRow0 = inp + (size_t)(rowBase + ty) * DIN;
    const float* pjCol  = proj + tx * 4;

    float4 ivA[8], ivB[8], pjA[4], pjB[4];
    auto load_step = [&](float4 iv[8], float4 pj[4], int kk) {
#pragma unroll
        for (int j = 0; j < 4; ++j) pj[j] = ld4(pjCol + (size_t)(kk + j) * DEMB);
#pragma unroll
        for (int i = 0; i < 8; ++i) iv[i] = ld4(inRow0 + (size_t)(8 * i) * DIN + kk);
    };
    auto fma_step = [&](const float4 iv[8], const float4 pj[4]) {
#pragma unroll
        for (int i = 0; i < 8; ++i) {
            const float* ivp = reinterpret_cast<const float*>(&iv[i]);
#pragma unroll
            for (int j = 0; j < 4; ++j) {
                acc1[i][0] = fmaf(ivp[j], pj[j].x, acc1[i][0]);
                acc1[i][1] = fmaf(ivp[j], pj[j].y, acc1[i][1]);
                acc1[i][2] = fmaf(ivp[j], pj[j].z, acc1[i][2]);
                acc1[i][3] = fmaf(ivp[j], pj[j].w, acc1[i][3]);
            }
        }
    };
    load_step(ivA, pjA, 0);
#pragma unroll 1
    for (int k = 0; k < DIN; k += 8) {
        load_step(ivB, pjB, k + 4);
        fma_step(ivA, pjA);
        if (k + 8 < DIN) load_step(ivA, pjA, k + 8);
        fma_step(ivB, pjB);
    }
#pragma unroll
    for (int i = 0; i < 8; ++i) {
        const int r = rowBase + ty + 8 * i;
        float ss = acc1[i][0] * acc1[i][0] + acc1[i][1] * acc1[i][1] +
                   acc1[i][2] * acc1[i][2] + acc1[i][3] * acc1[i][3];
#pragma unroll
        for (int mm = 1; mm < 32; mm <<= 1) ss += __shfl_xor(ss, mm, 64);
        if (tx == 0) rnw[r] = 1.0f / sqrtf(ss);
        *reinterpret_cast<float4*>(xw + (size_t)r * DEMB + tx * 4) =
            make_float4(acc1[i][0], acc1[i][1], acc1[i][2], acc1[i][3]);
    }
}

// ---------------------------------------------------------------------------
// Kernel 3: similarity + argmax. Block = (row-tile of 128, ONE codebook).
// Grid 2048, no LDS, no barriers: waves free-run, A-fragments from L1/L2.
// Flattened 128 k-steps, 2-slot register ping-pong (prefetch distance 2),
// 3 independent MFMA chains. 3 blocks/CU via __launch_bounds__(256,3).
// ---------------------------------------------------------------------------
__global__ __launch_bounds__(256, 3) void sim_kernel(
        const float* __restrict__ xw, const float* __restrict__ rnw,
        const unsigned short* __restrict__ cbA, const float* __restrict__ cbn,
        int* __restrict__ out) {
    const int tid = threadIdx.x;
    const int lane = tid & 63, wv = tid >> 6;
    const int kg = lane >> 5;
    const int cbi = blockIdx.x & 3;                       // codebook
    const int rowBase = (blockIdx.x >> 2) * 128;
    const int row = rowBase + wv * 32 + (lane & 31);

    // Hoist B fragments: normalize + split hi/lo this lane's x row.
    bf16x8 Bhi[8], Blo[8];
    {
        const float rn = rnw[row];
        const float* xr = xw + (size_t)row * DEMB;
#pragma unroll
        for (int kt = 0; kt < 8; ++kt) {
            const float4 f0 = ld4(xr + kt * 16 + kg * 8);
            const float4 f1 = ld4(xr + kt * 16 + kg * 8 + 4);
            const float xs[8] = {f0.x, f0.y, f0.z, f0.w, f1.x, f1.y, f1.z, f1.w};
            bf16x8 hv, lv;
#pragma unroll
            for (int e = 0; e < 8; ++e) {
                const float xn = xs[e] * rn;
                const unsigned short h = f2bf(xn);
                hv[e] = (short)h;
                lv[e] = (short)f2bf(xn - bf2f(h));
            }
            Bhi[kt] = hv; Blo[kt] = lv;
        }
    }

    // A-stream: 128 k-steps (16 tiles x 8 ksteps), byte offset s*2048 from
    // this codebook's base; per step hi at +0, lo at +1024 B (=512 shorts).
    const short* g = (const short*)cbA + (size_t)cbi * 16 * 8192 + lane * 8;

    bf16x8 Ah0, Al0, Ah1, Al1;   // 2-slot ping-pong
    auto lda = [&](bf16x8& h, bf16x8& l, int s) {
        h = *reinterpret_cast<const bf16x8*>(g + (size_t)s * 1024);
        l = *reinterpret_cast<const bf16x8*>(g + (size_t)s * 1024 + 512);
    };

    float t1 = -INFINITY, t2 = -INFINITY; int i1 = 0;

    lda(Ah0, Al0, 0);
    lda(Ah1, Al1, 1);

#pragma unroll 1
    for (int ct = 0; ct < 16; ++ct) {
        f32x16 accA, accB1, accB2;
#pragma unroll
        for (int r = 0; r < 16; ++r) { accA[r] = 0.0f; accB1[r] = 0.0f; accB2[r] = 0.0f; }
        const int s0 = ct * 8;
#pragma unroll
        for (int kt = 0; kt < 8; ++kt) {
            const int s = s0 + kt;
            if ((kt & 1) == 0) {
                accA  = __builtin_amdgcn_mfma_f32_32x32x16_bf16(Ah0, Bhi[kt], accA,  0, 0, 0);
                accB1 = __builtin_amdgcn_mfma_f32_32x32x16_bf16(Ah0, Blo[kt], accB1, 0, 0, 0);
                accB2 = __builtin_amdgcn_mfma_f32_32x32x16_bf16(Al0, Bhi[kt], accB2, 0, 0, 0);
                const int nx = (s + 2 < 128) ? s + 2 : 127;
                lda(Ah0, Al0, nx);                 // reload slot0 for step s+2
            } else {
                accA  = __builtin_amdgcn_mfma_f32_32x32x16_bf16(Ah1, Bhi[kt], accA,  0, 0, 0);
                accB1 = __builtin_amdgcn_mfma_f32_32x32x16_bf16(Ah1, Blo[kt], accB1, 0, 0, 0);
                accB2 = __builtin_amdgcn_mfma_f32_32x32x16_bf16(Al1, Bhi[kt], accB2, 0, 0, 0);
                const int nx = (s + 2 < 128) ? s + 2 : 127;
                lda(Ah1, Al1, nx);                 // reload slot1 for step s+2
            }
        }
        // top-2 update (local code index 0..511; ascending => first-max kept)
#pragma unroll
        for (int r = 0; r < 16; ++r) {
            const float v = (accA[r] + accB1[r]) + accB2[r];
            const int gidx = ct * 32 + ((r & 3) + 8 * (r >> 2) + 4 * kg);
            t2 = fmaxf(t2, fminf(v, t1));
            if (v > t1) { t1 = v; i1 = gidx; }
        }
    }

    // merge kg halves (lane L <-> L^32 hold same x-row, different codes)
    const float o1 = __shfl_xor(t1, 32, 64);
    const float o2 = __shfl_xor(t2, 32, 64);
    const int   oi = __shfl_xor(i1, 32, 64);
    const float m2 = fmaxf(fmaxf(t2, o2), fminf(t1, o1));
    if (o1 > t1 || (o1 == t1 && oi < i1)) { t1 = o1; i1 = oi; }
    const bool unc = (t1 - m2) < MARGIN;
    if (lane < 32 && !unc)
        out[(size_t)row * NCB + cbi] = i1;

    unsigned long long msk = __ballot(unc && lane < 32);
    while (msk) {                      // rare exact-f32 recheck
        const int r = __ffsll(msk) - 1; msk &= msk - 1;
        const int grow = rowBase + wv * 32 + r;
        const float* xr = xw + (size_t)grow * DEMB;
        float best = -INFINITY; int bi2 = 0;
#pragma unroll 1
        for (int j = 0; j < 8; ++j) {
            const int c = lane + 64 * j;
            const float* cv = cbn + ((size_t)cbi * MCODES + c) * DEMB;
            float s0 = 0, s1 = 0, s2 = 0, s3 = 0;
#pragma unroll
            for (int k = 0; k < DEMB; k += 4) {
                const float4 xk = ld4(xr + k);
                const float4 ck = ld4(cv + k);
                s0 = fmaf(xk.x, ck.x, s0); s1 = fmaf(xk.y, ck.y, s1);
                s2 = fmaf(xk.z, ck.z, s2); s3 = fmaf(xk.w, ck.w, s3);
            }
            const float s = (s0 + s1) + (s2 + s3);
            if (s > best) { best = s; bi2 = c; }
        }
#pragma unroll
        for (int mm = 1; mm < 64; mm <<= 1) {
            const float ov = __shfl_xor(best, mm, 64);
            const int   oc = __shfl_xor(bi2, mm, 64);
            if (ov > best || (ov == best && oc < bi2)) { best = ov; bi2 = oc; }
        }
        if (lane == 0) out[(size_t)grow * NCB + cbi] = bi2;
    }
}

// ---------------------------------------------------------------------------
// Fallback (ws too small): round-3 fused kernel (proven, 2 MB ws).
// ---------------------------------------------------------------------------
__global__ __launch_bounds__(256) void fused_quantize_kernel(
        const float* __restrict__ inp, const float* __restrict__ proj,
        const float* __restrict__ cbn, const unsigned short* __restrict__ cbA,
        int* __restrict__ out) {
    __shared__ float sX[128][132];
    __shared__ float sRn[128];
    const int tid = threadIdx.x;
    const int tx = tid & 31, ty = tid >> 5;
    const int rowBase = blockIdx.x * 128;

#pragma unroll 1
    for (int p = 0; p < 2; ++p) {
        float acc1[8][4];
#pragma unroll
        for (int i = 0; i < 8; ++i)
#pragma unroll
            for (int j = 0; j < 4; ++j) acc1[i][j] = 0.0f;
        const float* inRow0 = inp + (size_t)(rowBase + p * 64 + ty) * DIN;
        const float* pjCol  = proj + tx * 4;
        float4 ivA[8], ivB[8], pjA[4], pjB[4];
        auto load_step = [&](float4 iv[8], float4 pj[4], int kk) {
#pragma unroll
            for (int j = 0; j < 4; ++j) pj[j] = ld4(pjCol + (size_t)(kk + j) * DEMB);
#pragma unroll
            for (int i = 0; i < 8; ++i) iv[i] = ld4(inRow0 + (size_t)(8 * i) * DIN + kk);
        };
        auto fma_step = [&](const float4 iv[8], const float4 pj[4]) {
#pragma unroll
            for (int i = 0; i < 8; ++i) {
                const float* ivp = reinterpret_cast<const float*>(&iv[i]);
#pragma unroll
                for (int j = 0; j < 4; ++j) {
                    acc1[i][0] = fmaf(ivp[j], pj[j].x, acc1[i][0]);
                    acc1[i][1] = fmaf(ivp[j], pj[j].y, acc1[i][1]);
                    acc1[i][2] = fmaf(ivp[j], pj[j].z, acc1[i][2]);
                    acc1[i][3] = fmaf(ivp[j], pj[j].w, acc1[i][3]);
                }
            }
        };
        load_step(ivA, pjA, 0);
#pragma unroll 1
        for (int k = 0; k < DIN; k += 8) {
            load_step(ivB, pjB, k + 4);
            fma_step(ivA, pjA);
            if (k + 8 < DIN) load_step(ivA, pjA, k + 8);
            fma_step(ivB, pjB);
        }
#pragma unroll
        for (int i = 0; i < 8; ++i) {
            const int r = p * 64 + ty + 8 * i;
            float ss = acc1[i][0] * acc1[i][0] + acc1[i][1] * acc1[i][1] +
                       acc1[i][2] * acc1[i][2] + acc1[i][3] * acc1[i][3];
#pragma unroll
            for (int mm = 1; mm < 32; mm <<= 1) ss += __shfl_xor(ss, mm, 64);
            if (tx == 0) sRn[r] = 1.0f / sqrtf(ss);
            *reinterpret_cast<float4*>(&sX[r][tx * 4]) =
                make_float4(acc1[i][0], acc1[i][1], acc1[i][2], acc1[i][3]);
        }
    }
    __syncthreads();

    const int lane = tid & 63, wv = tid >> 6;
    const int kg = lane >> 5;
    const int rowL = wv * 32 + (lane & 31);
    bf16x8 Bhi[8], Blo[8];
    {
        const float rn = sRn[rowL];
#pragma unroll
        for (int kt = 0; kt < 8; ++kt) {
            const int k0 = kt * 16 + kg * 8;
            float4 f0 = ld4(&sX[rowL][k0]);
            float4 f1 = ld4(&sX[rowL][k0 + 4]);
            float xs[8] = {f0.x, f0.y, f0.z, f0.w, f1.x, f1.y, f1.z, f1.w};
            bf16x8 hv, lv;
#pragma unroll
            for (int e = 0; e < 8; ++e) {
                const float xn = xs[e] * rn;
                const unsigned short h = f2bf(xn);
                hv[e] = (short)h;
                lv[e] = (short)f2bf(xn - bf2f(h));
            }
            Bhi[kt] = hv; Blo[kt] = lv;
        }
    }
    float t1 = -INFINITY, t2 = -INFINITY; int i1 = 0;
    const short* pA = reinterpret_cast<const short*>(cbA) + (size_t)lane * 8;
#pragma unroll 1
    for (int ct = 0; ct < 64; ++ct) {
        if ((ct & 1) == 0) __syncthreads();
        const short* pct = pA + (size_t)ct * 8192;
        f32x16 accA, accB;
#pragma unroll
        for (int r = 0; r < 16; ++r) { accA[r] = 0.0f; accB[r] = 0.0f; }
#pragma unroll
        for (int kt = 0; kt < 8; ++kt) {
            const bf16x8 Ahi = *reinterpret_cast<const bf16x8*>(pct + kt * 1024);
            const bf16x8 Alo = *reinterpret_cast<const bf16x8*>(pct + kt * 1024 + 512);
            accA = __builtin_amdgcn_mfma_f32_32x32x16_bf16(Ahi, Bhi[kt], accA, 0, 0, 0);
            accB = __builtin_amdgcn_mfma_f32_32x32x16_bf16(Ahi, Blo[kt], accB, 0, 0, 0);
            accB = __builtin_amdgcn_mfma_f32_32x32x16_bf16(Alo, Bhi[kt], accB, 0, 0, 0);
        }
#pragma unroll
        for (int r = 0; r < 16; ++r) {
            const float v = accA[r] + accB[r];
            const int gidx = ct * 32 + ((r & 3) + 8 * (r >> 2) + 4 * kg);
            t2 = fmaxf(t2, fminf(v, t1));
            if (v > t1) { t1 = v; i1 = gidx; }
        }
        if ((ct & 15) == 15) {
            const int cbi = ct >> 4;
            const float o1 = __shfl_xor(t1, 32, 64);
            const float o2 = __shfl_xor(t2, 32, 64);
            const int   oi = __shfl_xor(i1, 32, 64);
            const float m2 = fmaxf(fmaxf(t2, o2), fminf(t1, o1));
            if (o1 > t1 || (o1 == t1 && oi < i1)) { t1 = o1; i1 = oi; }
            const bool unc = (t1 - m2) < MARGIN;
            if (lane < 32 && !unc)
                out[(size_t)(rowBase + rowL) * NCB + cbi] = i1 - cbi * MCODES;
            unsigned long long msk = __ballot(unc && lane < 32);
            while (msk) {
                const int r = __ffsll(msk) - 1; msk &= msk - 1;
                const int rl = wv * 32 + r;
                float best = -INFINITY; int bi = 0;
#pragma unroll 1
                for (int j = 0; j < 8; ++j) {
                    const int c = lane + 64 * j;
                    const float* cv = cbn + ((size_t)cbi * MCODES + c) * DEMB;
                    float s0 = 0, s1 = 0, s2 = 0, s3 = 0;
#pragma unroll
                    for (int k = 0; k < DEMB; k += 4) {
                        const float4 xk = ld4(&sX[rl][k]);
                        const float4 ck = ld4(cv + k);
                        s0 = fmaf(xk.x, ck.x, s0); s1 = fmaf(xk.y, ck.y, s1);
                        s2 = fmaf(xk.z, ck.z, s2); s3 = fmaf(xk.w, ck.w, s3);
                    }
                    const float s = (s0 + s1) + (s2 + s3);
                    if (s > best) { best = s; bi = c; }
                }
#pragma unroll
                for (int mm = 1; mm < 64; mm <<= 1) {
                    const float ov = __shfl_xor(best, mm, 64);
                    const int   oc = __shfl_xor(bi, mm, 64);
                    if (ov > best || (ov == best && oc < bi)) { best = ov; bi = oc; }
                }
                if (lane == 0) out[(size_t)(rowBase + rl) * NCB + cbi] = bi;
            }
            t1 = -INFINITY; t2 = -INFINITY; i1 = 0;
        }
    }
}

// ---------------------------------------------------------------------------
extern "C" void kernel_launch(void* const* d_in, const int* in_sizes, int n_in,
                              void* d_out, int out_size, void* d_ws, size_t ws_size,
                              hipStream_t stream) {
    const float* inp  = (const float*)d_in[0];   // [8,16,512,256]
    const float* proj = (const float*)d_in[1];   // [256,128]
    const float* cb   = (const float*)d_in[2];   // [4,512,128]
    int* out = (int*)d_out;                      // [8,16,512,4] int32

    char* ws = (char*)d_ws;
    float* cbn = (float*)ws;                               // 1 MB
    unsigned short* cbA = (unsigned short*)(ws + (1 << 20)); // 1 MB
    float* rnw = (float*)(ws + (2 << 20));                 // 256 KB
    float* xw  = (float*)(ws + (2 << 20) + (1 << 18));     // 32 MB
    const size_t need = (size_t)(2 << 20) + (1 << 18) + (size_t)65536 * DEMB * 4;

    hipLaunchKernelGGL(prep_codebook, dim3(NCODE / 4), dim3(256), 0, stream,
                       cb, cbn, cbA);
    if (ws_size >= need) {
        hipLaunchKernelGGL(project_kernel, dim3(1024), dim3(256), 0, stream,
                           inp, proj, xw, rnw);
        hipLaunchKernelGGL(sim_kernel, dim3(512 * NCB), dim3(256), 0, stream,
                           xw, rnw, cbA, cbn, out);
    } else {
        hipLaunchKernelGGL(fused_quantize_kernel, dim3(512), dim3(256), 0, stream,
                           inp, proj, cbn, cbA, out);
    }
}

// Round 6
// 269.550 us; speedup vs baseline: 1.2446x; 1.2446x over previous
//
#include <hip/hip_runtime.h>
#include <math.h>

#define DIN    256
#define DEMB   128
#define NCB    4
#define MCODES 512
#define NCODE  2048
#define MARGIN 1.5e-4f      // >10x rigorous split-bf16 error bound (~1.3e-5)

using bf16x8 = __attribute__((ext_vector_type(8))) short;
using f32x16 = __attribute__((ext_vector_type(16))) float;

static __device__ __forceinline__ unsigned short f2bf(float f) {   // RNE f32->bf16
    unsigned u = __float_as_uint(f);
    u += 0x7FFFu + ((u >> 16) & 1u);
    return (unsigned short)(u >> 16);
}
static __device__ __forceinline__ float bf2f(unsigned short h) {
    return __uint_as_float(((unsigned)h) << 16);
}
static __device__ __forceinline__ float4 ld4(const float* p) {
    return *reinterpret_cast<const float4*>(p);
}
// async global->LDS DMA, 16B per lane, wave-uniform LDS base (guide §5)
static __device__ __forceinline__ void gload_lds16(const void* g, void* l) {
    __builtin_amdgcn_global_load_lds(
        (const __attribute__((address_space(1))) void*)g,
        (__attribute__((address_space(3))) void*)l, 16, 0, 0);
}

// ---------------------------------------------------------------------------
// Kernel 1: normalize codebook rows; emit (a) f32 copy for exact recheck,
// (b) hi/lo bf16 split in mfma_32x32x16 A-fragment order (tile ct = 16 KB
// contiguous: [kt 0..8][hl 0..2][lane 0..64][8 shorts]).
// ---------------------------------------------------------------------------
__global__ __launch_bounds__(256) void prep_codebook(
        const float* __restrict__ cb, float* __restrict__ cbn,
        unsigned short* __restrict__ cbA) {
    const int w = threadIdx.x >> 6, lane = threadIdx.x & 63;
    const int code = blockIdx.x * 4 + w;                 // 0..2047
    const float2 v = reinterpret_cast<const float2*>(cb + (size_t)code * DEMB)[lane];
    float ss = v.x * v.x + v.y * v.y;
#pragma unroll
    for (int m = 1; m < 64; m <<= 1) ss += __shfl_xor(ss, m, 64);
    const float rn = 1.0f / sqrtf(ss);
    const float x0 = v.x * rn, x1 = v.y * rn;
    reinterpret_cast<float2*>(cbn + (size_t)code * DEMB)[lane] = make_float2(x0, x1);

    const unsigned short h0 = f2bf(x0), h1 = f2bf(x1);
    const unsigned short l0 = f2bf(x0 - bf2f(h0)), l1 = f2bf(x1 - bf2f(h1));
    const int ct = code >> 5, ci = code & 31;
    const int kt = lane >> 3, g = (lane >> 2) & 1, i = 2 * (lane & 3);
    const size_t base = ((size_t)ct * 1024 + kt * 128 + g * 32 + ci) * 8 + i;
    *reinterpret_cast<ushort2*>(cbA + base)       = make_ushort2(h0, h1);  // hi
    *reinterpret_cast<ushort2*>(cbA + base + 512) = make_ushort2(l0, l1);  // lo
}

// ---------------------------------------------------------------------------
// Kernel 2: projection x = inp @ proj (f32 VALU, register-pipelined).
// ---------------------------------------------------------------------------
__global__ __launch_bounds__(256) void project_kernel(
        const float* __restrict__ inp, const float* __restrict__ proj,
        float* __restrict__ xw, float* __restrict__ rnw) {
    const int tid = threadIdx.x, tx = tid & 31, ty = tid >> 5;
    const int rowBase = blockIdx.x * 64;

    float acc1[8][4];
#pragma unroll
    for (int i = 0; i < 8; ++i)
#pragma unroll
        for (int j = 0; j < 4; ++j) acc1[i][j] = 0.0f;

    const float* inRow0 = inp + (size_t)(rowBase + ty) * DIN;
    const float* pjCol  = proj + tx * 4;

    float4 ivA[8], ivB[8], pjA[4], pjB[4];
    auto load_step = [&](float4 iv[8], float4 pj[4], int kk) {
#pragma unroll
        for (int j = 0; j < 4; ++j) pj[j] = ld4(pjCol + (size_t)(kk + j) * DEMB);
#pragma unroll
        for (int i = 0; i < 8; ++i) iv[i] = ld4(inRow0 + (size_t)(8 * i) * DIN + kk);
    };
    auto fma_step = [&](const float4 iv[8], const float4 pj[4]) {
#pragma unroll
        for (int i = 0; i < 8; ++i) {
            const float* ivp = reinterpret_cast<const float*>(&iv[i]);
#pragma unroll
            for (int j = 0; j < 4; ++j) {
                acc1[i][0] = fmaf(ivp[j], pj[j].x, acc1[i][0]);
                acc1[i][1] = fmaf(ivp[j], pj[j].y, acc1[i][1]);
                acc1[i][2] = fmaf(ivp[j], pj[j].z, acc1[i][2]);
                acc1[i][3] = fmaf(ivp[j], pj[j].w, acc1[i][3]);
            }
        }
    };
    load_step(ivA, pjA, 0);
#pragma unroll 1
    for (int k = 0; k < DIN; k += 8) {
        load_step(ivB, pjB, k + 4);
        fma_step(ivA, pjA);
        if (k + 8 < DIN) load_step(ivA, pjA, k + 8);
        fma_step(ivB, pjB);
    }
#pragma unroll
    for (int i = 0; i < 8; ++i) {
        const int r = rowBase + ty + 8 * i;
        float ss = acc1[i][0] * acc1[i][0] + acc1[i][1] * acc1[i][1] +
                   acc1[i][2] * acc1[i][2] + acc1[i][3] * acc1[i][3];
#pragma unroll
        for (int mm = 1; mm < 32; mm <<= 1) ss += __shfl_xor(ss, mm, 64);
        if (tx == 0) rnw[r] = 1.0f / sqrtf(ss);
        *reinterpret_cast<float4*>(xw + (size_t)r * DEMB + tx * 4) =
            make_float4(acc1[i][0], acc1[i][1], acc1[i][2], acc1[i][3]);
    }
}

// ---------------------------------------------------------------------------
// Kernel 3: similarity + margin argmax. Block = (128 rows, ONE codebook),
// grid 2048. A-tiles flow through a 3-buffer LDS pipeline fed by
// global_load_lds (deep DMA queue, zero VGPR): per tile
//   vmcnt(4) [tile ct landed, ct+1 in flight] -> s_barrier -> stage(ct+2)
//   -> ds_read + 24 MFMA + top-2 update.
// vmcnt never drains to 0 mid-loop; single raw barrier per tile.
// Uncertain rows are appended to a list for the recheck kernel (no serial
// recheck tail inside sim waves).
// ---------------------------------------------------------------------------
__global__ __launch_bounds__(256) void sim_kernel(
        const float* __restrict__ xw, const float* __restrict__ rnw,
        const unsigned short* __restrict__ cbA,
        int* __restrict__ out, int* __restrict__ unc_cnt,
        int* __restrict__ unc_list) {
    __shared__ __align__(16) short sA[3][8192];   // 3 x 16 KB tile buffers
    const int tid = threadIdx.x;
    const int lane = tid & 63, wv = tid >> 6;
    const int kg = lane >> 5;
    const int cbi = blockIdx.x & 3;
    const int rowBase = (blockIdx.x >> 2) * 128;
    const int row = rowBase + wv * 32 + (lane & 31);

    const short* gA = (const short*)cbA + (size_t)cbi * 16 * 8192;

    auto stage = [&](int buf, int t) {   // 16 KB tile, 4 DMA instrs/thread
        const short* g = gA + (size_t)t * 8192 + wv * 512 + lane * 8;
        short* l = &sA[buf][wv * 512];
#pragma unroll
        for (int c = 0; c < 4; ++c)
            gload_lds16(g + c * 2048, l + c * 2048);
    };

    stage(0, 0);
    stage(1, 1);

    // B-frag hoist: normalize + split hi/lo this lane's x row (once/wave).
    bf16x8 Bhi[8], Blo[8];
    {
        const float rn = rnw[row];
        const float* xr = xw + (size_t)row * DEMB;
#pragma unroll
        for (int kt = 0; kt < 8; ++kt) {
            const float4 f0 = ld4(xr + kt * 16 + kg * 8);
            const float4 f1 = ld4(xr + kt * 16 + kg * 8 + 4);
            const float xs[8] = {f0.x, f0.y, f0.z, f0.w, f1.x, f1.y, f1.z, f1.w};
            bf16x8 hv, lv;
#pragma unroll
            for (int e = 0; e < 8; ++e) {
                const float xn = xs[e] * rn;
                const unsigned short h = f2bf(xn);
                hv[e] = (short)h;
                lv[e] = (short)f2bf(xn - bf2f(h));
            }
            Bhi[kt] = hv; Blo[kt] = lv;
        }
    }

    float t1 = -INFINITY, t2 = -INFINITY; int i1 = 0;

#pragma unroll 1
    for (int ct = 0; ct < 16; ++ct) {
        if (ct < 15) asm volatile("s_waitcnt vmcnt(4)" ::: "memory");
        else         asm volatile("s_waitcnt vmcnt(0)" ::: "memory");
        __builtin_amdgcn_s_barrier();       // all waves' tile-ct DMA visible
        asm volatile("" ::: "memory");
        if (ct + 2 < 16) stage((ct + 2) % 3, ct + 2);  // overwrites buf read at ct-1

        f32x16 accA, accB1, accB2;
#pragma unroll
        for (int r = 0; r < 16; ++r) { accA[r] = 0.0f; accB1[r] = 0.0f; accB2[r] = 0.0f; }
        const short* pa = &sA[ct % 3][lane * 8];
#pragma unroll
        for (int kt = 0; kt < 8; ++kt) {
            const bf16x8 Ahi = *reinterpret_cast<const bf16x8*>(pa + kt * 1024);
            const bf16x8 Alo = *reinterpret_cast<const bf16x8*>(pa + kt * 1024 + 512);
            accA  = __builtin_amdgcn_mfma_f32_32x32x16_bf16(Ahi, Bhi[kt], accA,  0, 0, 0);
            accB1 = __builtin_amdgcn_mfma_f32_32x32x16_bf16(Ahi, Blo[kt], accB1, 0, 0, 0);
            accB2 = __builtin_amdgcn_mfma_f32_32x32x16_bf16(Alo, Bhi[kt], accB2, 0, 0, 0);
        }
        // running top-2 (gidx ascending within lane => first-max kept)
#pragma unroll
        for (int r = 0; r < 16; ++r) {
            const float v = (accA[r] + accB1[r]) + accB2[r];
            const int gidx = ct * 32 + ((r & 3) + 8 * (r >> 2) + 4 * kg);
            t2 = fmaxf(t2, fminf(v, t1));
            if (v > t1) { t1 = v; i1 = gidx; }
        }
    }

    // merge kg halves (lane L <-> L^32: same x-row, disjoint codes)
    const float o1 = __shfl_xor(t1, 32, 64);
    const float o2 = __shfl_xor(t2, 32, 64);
    const int   oi = __shfl_xor(i1, 32, 64);
    const float m2 = fmaxf(fmaxf(t2, o2), fminf(t1, o1));
    if (o1 > t1 || (o1 == t1 && oi < i1)) { t1 = o1; i1 = oi; }
    const bool unc = (t1 - m2) < MARGIN;
    if (lane < 32 && !unc)
        out[(size_t)row * NCB + cbi] = i1;

    unsigned long long msk = __ballot(unc && lane < 32);
    if (lane == 0 && msk) {
        const int n = __popcll(msk);
        int base = atomicAdd(unc_cnt, n);
        while (msk) {
            const int r = __ffsll(msk) - 1; msk &= msk - 1;
            unc_list[base++] = ((rowBase + wv * 32 + r) << 2) | cbi;
        }
    }
}

// ---------------------------------------------------------------------------
// Kernel 4: exact-f32 recheck of uncertain (row, codebook) pairs.
// One wave per item, grid-stride. Same scan order / tie rules as inline
// version (lane handles codes lane+64j ascending; butterfly prefers lower
// index on exact ties) -> matches jnp.argmax first-max semantics.
// ---------------------------------------------------------------------------
__global__ __launch_bounds__(256) void recheck_kernel(
        const float* __restrict__ xw, const float* __restrict__ cbn,
        const int* __restrict__ unc_cnt, const int* __restrict__ unc_list,
        int* __restrict__ out) {
    const int lane = threadIdx.x & 63, wv = threadIdx.x >> 6;
    const int n = *unc_cnt;
    for (int it = blockIdx.x * 4 + wv; it < n; it += gridDim.x * 4) {
        const int item = unc_list[it];
        const int row = item >> 2, cbi = item & 3;
        const float* xr = xw + (size_t)row * DEMB;
        float best = -INFINITY; int bi = 0;
#pragma unroll 1
        for (int j = 0; j < 8; ++j) {
            const int c = lane + 64 * j;
            const float* cv = cbn + ((size_t)cbi * MCODES + c) * DEMB;
            float s0 = 0, s1 = 0, s2 = 0, s3 = 0;
#pragma unroll
            for (int k = 0; k < DEMB; k += 4) {
                const float4 xk = ld4(xr + k);
                const float4 ck = ld4(cv + k);
                s0 = fmaf(xk.x, ck.x, s0); s1 = fmaf(xk.y, ck.y, s1);
                s2 = fmaf(xk.z, ck.z, s2); s3 = fmaf(xk.w, ck.w, s3);
            }
            const float s = (s0 + s1) + (s2 + s3);
            if (s > best) { best = s; bi = c; }
        }
#pragma unroll
        for (int mm = 1; mm < 64; mm <<= 1) {
            const float ov = __shfl_xor(best, mm, 64);
            const int   oc = __shfl_xor(bi, mm, 64);
            if (ov > best || (ov == best && oc < bi)) { best = ov; bi = oc; }
        }
        if (lane == 0) out[(size_t)row * NCB + cbi] = bi;
    }
}

// ---------------------------------------------------------------------------
// Fallback (ws too small): round-3 fused kernel (proven, 2 MB ws).
// ---------------------------------------------------------------------------
__global__ __launch_bounds__(256) void fused_quantize_kernel(
        const float* __restrict__ inp, const float* __restrict__ proj,
        const float* __restrict__ cbn, const unsigned short* __restrict__ cbA,
        int* __restrict__ out) {
    __shared__ float sX[128][132];
    __shared__ float sRn[128];
    const int tid = threadIdx.x;
    const int tx = tid & 31, ty = tid >> 5;
    const int rowBase = blockIdx.x * 128;

#pragma unroll 1
    for (int p = 0; p < 2; ++p) {
        float acc1[8][4];
#pragma unroll
        for (int i = 0; i < 8; ++i)
#pragma unroll
            for (int j = 0; j < 4; ++j) acc1[i][j] = 0.0f;
        const float* inRow0 = inp + (size_t)(rowBase + p * 64 + ty) * DIN;
        const float* pjCol  = proj + tx * 4;
        float4 ivA[8], ivB[8], pjA[4], pjB[4];
        auto load_step = [&](float4 iv[8], float4 pj[4], int kk) {
#pragma unroll
            for (int j = 0; j < 4; ++j) pj[j] = ld4(pjCol + (size_t)(kk + j) * DEMB);
#pragma unroll
            for (int i = 0; i < 8; ++i) iv[i] = ld4(inRow0 + (size_t)(8 * i) * DIN + kk);
        };
        auto fma_step = [&](const float4 iv[8], const float4 pj[4]) {
#pragma unroll
            for (int i = 0; i < 8; ++i) {
                const float* ivp = reinterpret_cast<const float*>(&iv[i]);
#pragma unroll
                for (int j = 0; j < 4; ++j) {
                    acc1[i][0] = fmaf(ivp[j], pj[j].x, acc1[i][0]);
                    acc1[i][1] = fmaf(ivp[j], pj[j].y, acc1[i][1]);
                    acc1[i][2] = fmaf(ivp[j], pj[j].z, acc1[i][2]);
                    acc1[i][3] = fmaf(ivp[j], pj[j].w, acc1[i][3]);
                }
            }
        };
        load_step(ivA, pjA, 0);
#pragma unroll 1
        for (int k = 0; k < DIN; k += 8) {
            load_step(ivB, pjB, k + 4);
            fma_step(ivA, pjA);
            if (k + 8 < DIN) load_step(ivA, pjA, k + 8);
            fma_step(ivB, pjB);
        }
#pragma unroll
        for (int i = 0; i < 8; ++i) {
            const int r = p * 64 + ty + 8 * i;
            float ss = acc1[i][0] * acc1[i][0] + acc1[i][1] * acc1[i][1] +
                       acc1[i][2] * acc1[i][2] + acc1[i][3] * acc1[i][3];
#pragma unroll
            for (int mm = 1; mm < 32; mm <<= 1) ss += __shfl_xor(ss, mm, 64);
            if (tx == 0) sRn[r] = 1.0f / sqrtf(ss);
            *reinterpret_cast<float4*>(&sX[r][tx * 4]) =
                make_float4(acc1[i][0], acc1[i][1], acc1[i][2], acc1[i][3]);
        }
    }
    __syncthreads();

    const int lane = tid & 63, wv = tid >> 6;
    const int kg = lane >> 5;
    const int rowL = wv * 32 + (lane & 31);
    bf16x8 Bhi[8], Blo[8];
    {
        const float rn = sRn[rowL];
#pragma unroll
        for (int kt = 0; kt < 8; ++kt) {
            const int k0 = kt * 16 + kg * 8;
            float4 f0 = ld4(&sX[rowL][k0]);
            float4 f1 = ld4(&sX[rowL][k0 + 4]);
            float xs[8] = {f0.x, f0.y, f0.z, f0.w, f1.x, f1.y, f1.z, f1.w};
            bf16x8 hv, lv;
#pragma unroll
            for (int e = 0; e < 8; ++e) {
                const float xn = xs[e] * rn;
                const unsigned short h = f2bf(xn);
                hv[e] = (short)h;
                lv[e] = (short)f2bf(xn - bf2f(h));
            }
            Bhi[kt] = hv; Blo[kt] = lv;
        }
    }
    float t1 = -INFINITY, t2 = -INFINITY; int i1 = 0;
    const short* pA = reinterpret_cast<const short*>(cbA) + (size_t)lane * 8;
#pragma unroll 1
    for (int ct = 0; ct < 64; ++ct) {
        if ((ct & 1) == 0) __syncthreads();
        const short* pct = pA + (size_t)ct * 8192;
        f32x16 accA, accB;
#pragma unroll
        for (int r = 0; r < 16; ++r) { accA[r] = 0.0f; accB[r] = 0.0f; }
#pragma unroll
        for (int kt = 0; kt < 8; ++kt) {
            const bf16x8 Ahi = *reinterpret_cast<const bf16x8*>(pct + kt * 1024);
            const bf16x8 Alo = *reinterpret_cast<const bf16x8*>(pct + kt * 1024 + 512);
            accA = __builtin_amdgcn_mfma_f32_32x32x16_bf16(Ahi, Bhi[kt], accA, 0, 0, 0);
            accB = __builtin_amdgcn_mfma_f32_32x32x16_bf16(Ahi, Blo[kt], accB, 0, 0, 0);
            accB = __builtin_amdgcn_mfma_f32_32x32x16_bf16(Alo, Bhi[kt], accB, 0, 0, 0);
        }
#pragma unroll
        for (int r = 0; r < 16; ++r) {
            const float v = accA[r] + accB[r];
            const int gidx = ct * 32 + ((r & 3) + 8 * (r >> 2) + 4 * kg);
            t2 = fmaxf(t2, fminf(v, t1));
            if (v > t1) { t1 = v; i1 = gidx; }
        }
        if ((ct & 15) == 15) {
            const int cbi = ct >> 4;
            const float o1 = __shfl_xor(t1, 32, 64);
            const float o2 = __shfl_xor(t2, 32, 64);
            const int   oi = __shfl_xor(i1, 32, 64);
            const float m2 = fmaxf(fmaxf(t2, o2), fminf(t1, o1));
            if (o1 > t1 || (o1 == t1 && oi < i1)) { t1 = o1; i1 = oi; }
            const bool unc = (t1 - m2) < MARGIN;
            if (lane < 32 && !unc)
                out[(size_t)(rowBase + rowL) * NCB + cbi] = i1 - cbi * MCODES;
            unsigned long long msk = __ballot(unc && lane < 32);
            while (msk) {
                const int r = __ffsll(msk) - 1; msk &= msk - 1;
                const int rl = wv * 32 + r;
                float best = -INFINITY; int bi = 0;
#pragma unroll 1
                for (int j = 0; j < 8; ++j) {
                    const int c = lane + 64 * j;
                    const float* cv = cbn + ((size_t)cbi * MCODES + c) * DEMB;
                    float s0 = 0, s1 = 0, s2 = 0, s3 = 0;
#pragma unroll
                    for (int k = 0; k < DEMB; k += 4) {
                        const float4 xk = ld4(&sX[rl][k]);
                        const float4 ck = ld4(cv + k);
                        s0 = fmaf(xk.x, ck.x, s0); s1 = fmaf(xk.y, ck.y, s1);
                        s2 = fmaf(xk.z, ck.z, s2); s3 = fmaf(xk.w, ck.w, s3);
                    }
                    const float s = (s0 + s1) + (s2 + s3);
                    if (s > best) { best = s; bi = c; }
                }
#pragma unroll
                for (int mm = 1; mm < 64; mm <<= 1) {
                    const float ov = __shfl_xor(best, mm, 64);
                    const int   oc = __shfl_xor(bi, mm, 64);
                    if (ov > best || (ov == best && oc < bi)) { best = ov; bi = oc; }
                }
                if (lane == 0) out[(size_t)(rowBase + rl) * NCB + cbi] = bi;
            }
            t1 = -INFINITY; t2 = -INFINITY; i1 = 0;
        }
    }
}

// ---------------------------------------------------------------------------
extern "C" void kernel_launch(void* const* d_in, const int* in_sizes, int n_in,
                              void* d_out, int out_size, void* d_ws, size_t ws_size,
                              hipStream_t stream) {
    const float* inp  = (const float*)d_in[0];   // [8,16,512,256]
    const float* proj = (const float*)d_in[1];   // [256,128]
    const float* cb   = (const float*)d_in[2];   // [4,512,128]
    int* out = (int*)d_out;                      // [8,16,512,4] int32

    char* ws = (char*)d_ws;
    float* cbn = (float*)ws;                                     // 1 MB
    unsigned short* cbA = (unsigned short*)(ws + (1 << 20));     // 1 MB
    float* rnw = (float*)(ws + (2 << 20));                       // 256 KB
    float* xw  = (float*)(ws + (2 << 20) + (1 << 18));           // 32 MB
    const size_t off_cnt = (size_t)(2 << 20) + (1 << 18) + ((size_t)32 << 20);
    int* unc_cnt  = (int*)(ws + off_cnt);                        // 4 B (pad 256)
    int* unc_list = (int*)(ws + off_cnt + 256);                  // 1 MB
    const size_t need = off_cnt + 256 + (1 << 20);

    hipLaunchKernelGGL(prep_codebook, dim3(NCODE / 4), dim3(256), 0, stream,
                       cb, cbn, cbA);
    if (ws_size >= need) {
        hipMemsetAsync(unc_cnt, 0, 4, stream);
        hipLaunchKernelGGL(project_kernel, dim3(1024), dim3(256), 0, stream,
                           inp, proj, xw, rnw);
        hipLaunchKernelGGL(sim_kernel, dim3(512 * NCB), dim3(256), 0, stream,
                           xw, rnw, cbA, out, unc_cnt, unc_list);
        hipLaunchKernelGGL(recheck_kernel, dim3(512), dim3(256), 0, stream,
                           xw, cbn, unc_cnt, unc_list, out);
    } else {
        hipLaunchKernelGGL(fused_quantize_kernel, dim3(512), dim3(256), 0, stream,
                           inp, proj, cbn, cbA, out);
    }
}

// Round 7
// 231.286 us; speedup vs baseline: 1.4505x; 1.1654x over previous
//
#include <hip/hip_runtime.h>
#include <math.h>

#define DIN    256
#define DEMB   128
#define NCB    4
#define MCODES 512
#define NCODE  2048
#define MARGIN 1.5e-4f      // >10x rigorous split-bf16 error bound (~1.3e-5)

using bf16x8 = __attribute__((ext_vector_type(8))) short;
using f32x16 = __attribute__((ext_vector_type(16))) float;

static __device__ __forceinline__ unsigned short f2bf(float f) {   // RNE f32->bf16
    unsigned u = __float_as_uint(f);
    u += 0x7FFFu + ((u >> 16) & 1u);
    return (unsigned short)(u >> 16);
}
static __device__ __forceinline__ float bf2f(unsigned short h) {
    return __uint_as_float(((unsigned)h) << 16);
}
static __device__ __forceinline__ float4 ld4(const float* p) {
    return *reinterpret_cast<const float4*>(p);
}
// async global->LDS DMA, 16B per lane, wave-uniform LDS base (guide §5)
static __device__ __forceinline__ void gload_lds16(const void* g, void* l) {
    __builtin_amdgcn_global_load_lds(
        (const __attribute__((address_space(1))) void*)g,
        (__attribute__((address_space(3))) void*)l, 16, 0, 0);
}

// ---------------------------------------------------------------------------
// Kernel 1: normalize codebook rows; emit (a) f32 copy for exact recheck,
// (b) hi/lo bf16 split in mfma_32x32x16 A-fragment order (tile ct = 16 KB
// contiguous: [kt 0..8][hl 0..2][lane 0..64][8 shorts]).
// ---------------------------------------------------------------------------
__global__ __launch_bounds__(256) void prep_codebook(
        const float* __restrict__ cb, float* __restrict__ cbn,
        unsigned short* __restrict__ cbA) {
    const int w = threadIdx.x >> 6, lane = threadIdx.x & 63;
    const int code = blockIdx.x * 4 + w;                 // 0..2047
    const float2 v = reinterpret_cast<const float2*>(cb + (size_t)code * DEMB)[lane];
    float ss = v.x * v.x + v.y * v.y;
#pragma unroll
    for (int m = 1; m < 64; m <<= 1) ss += __shfl_xor(ss, m, 64);
    const float rn = 1.0f / sqrtf(ss);
    const float x0 = v.x * rn, x1 = v.y * rn;
    reinterpret_cast<float2*>(cbn + (size_t)code * DEMB)[lane] = make_float2(x0, x1);

    const unsigned short h0 = f2bf(x0), h1 = f2bf(x1);
    const unsigned short l0 = f2bf(x0 - bf2f(h0)), l1 = f2bf(x1 - bf2f(h1));
    const int ct = code >> 5, ci = code & 31;
    const int kt = lane >> 3, g = (lane >> 2) & 1, i = 2 * (lane & 3);
    const size_t base = ((size_t)ct * 1024 + kt * 128 + g * 32 + ci) * 8 + i;
    *reinterpret_cast<ushort2*>(cbA + base)       = make_ushort2(h0, h1);  // hi
    *reinterpret_cast<ushort2*>(cbA + base + 512) = make_ushort2(l0, l1);  // lo
}

// ---------------------------------------------------------------------------
// Kernel 1b: 3-way split (hi/mid/lo bf16) of projector^T in A-fragment order:
// pjA[(mt*16+kt)*3 + part][lane = g*32 + ci][8 elems], value proj[k][m],
// m = mt*32+ci, k = kt*16 + g*8 + i.  192 KB total, L2-hot.
// ---------------------------------------------------------------------------
__global__ __launch_bounds__(256) void prep_proj(
        const float* __restrict__ proj, unsigned short* __restrict__ pjA) {
    const int t = blockIdx.x * 256 + threadIdx.x;      // 4096 threads
    const int ci = t & 31, g = (t >> 5) & 1, kt = (t >> 6) & 15, mt = t >> 10;
    const int m = mt * 32 + ci;
    const size_t base = ((size_t)(mt * 16 + kt) * 3) * 512 + (size_t)(g * 32 + ci) * 8;
#pragma unroll
    for (int i = 0; i < 8; ++i) {
        const float v = proj[(size_t)(kt * 16 + g * 8 + i) * DEMB + m];
        const unsigned short h = f2bf(v);
        const float r1 = v - bf2f(h);                  // exact (Sterbenz)
        const unsigned short md = f2bf(r1);
        const float r2 = r1 - bf2f(md);                // exact
        pjA[base + i]        = h;
        pjA[base + 512 + i]  = md;
        pjA[base + 1024 + i] = f2bf(r2);
    }
}

// ---------------------------------------------------------------------------
// Kernel 2 (new): projection x = inp @ proj via 6-pass split-bf16 MFMA
// (hh | hm+mh | hl+lh+mm) -> f32-matmul-accuracy x~ (dropped terms <= 2^-26).
// Block 256 thr = 4 waves x 32 rows. A (projT split) through a 3-buffer LDS
// pipeline (wave w stages mt=w, 3 parts = 3 DMA); input rows read per-lane
// with 1-step register prefetch. Counted vmcnt(3); 1 barrier/kt; kt fully
// unrolled (compile-time ping-pong).
// ---------------------------------------------------------------------------
__global__ __launch_bounds__(256) void project_mfma(
        const float* __restrict__ inp, const unsigned short* __restrict__ pjA,
        float* __restrict__ xw, float* __restrict__ rnw) {
    __shared__ __align__(16) short sA[3][6144];        // 3 x 12 KB: [mt][part][lane][8]
    const int tid = threadIdx.x;
    const int lane = tid & 63, wv = tid >> 6, kg = lane >> 5;
    const int row = blockIdx.x * 128 + wv * 32 + (lane & 31);
    const float* xr = inp + (size_t)row * DIN;

    auto stageA = [&](int buf, int kt) {               // wave wv stages mt=wv
#pragma unroll
        for (int c = 0; c < 3; ++c) {
            const unsigned short* g =
                pjA + ((size_t)(wv * 16 + kt) * 3 + c) * 512 + (size_t)lane * 8;
            gload_lds16(g, &sA[buf][(wv * 3 + c) * 512]);
        }
    };
    auto ldin = [&](float4& a, float4& b, int kt) {
        a = ld4(xr + kt * 16 + kg * 8);
        b = ld4(xr + kt * 16 + kg * 8 + 4);
    };
    auto split8 = [&](const float4& a, const float4& b,
                      bf16x8& H, bf16x8& M, bf16x8& L) {
        const float xs[8] = {a.x, a.y, a.z, a.w, b.x, b.y, b.z, b.w};
#pragma unroll
        for (int e = 0; e < 8; ++e) {
            const float v = xs[e];
            const unsigned short h = f2bf(v);
            const float r1 = v - bf2f(h);
            const unsigned short md = f2bf(r1);
            const float r2 = r1 - bf2f(md);
            H[e] = (short)h; M[e] = (short)md; L[e] = (short)f2bf(r2);
        }
    };

    f32x16 accP[4], accQ[4];
#pragma unroll
    for (int mt = 0; mt < 4; ++mt)
#pragma unroll
        for (int r = 0; r < 16; ++r) { accP[mt][r] = 0.0f; accQ[mt][r] = 0.0f; }

    float4 nA0, nA1, nB0, nB1;
    stageA(0, 0);
    ldin(nA0, nA1, 0);
    stageA(1, 1);

#pragma unroll
    for (int kt = 0; kt < 16; ++kt) {
        if (kt < 15) asm volatile("s_waitcnt vmcnt(3)" ::: "memory");
        else         asm volatile("s_waitcnt vmcnt(0)" ::: "memory");
        __builtin_amdgcn_s_barrier();
        asm volatile("" ::: "memory");

        const float4 c0 = (kt & 1) ? nB0 : nA0;        // compile-time (full unroll)
        const float4 c1 = (kt & 1) ? nB1 : nA1;
        if (kt < 15) {
            if (kt & 1) ldin(nA0, nA1, kt + 1);
            else        ldin(nB0, nB1, kt + 1);
        }
        if (kt + 2 < 16) stageA((kt + 2) % 3, kt + 2);

        bf16x8 Bh, Bm, Bl;
        split8(c0, c1, Bh, Bm, Bl);
        const int bc = kt % 3;
#pragma unroll
        for (int mt = 0; mt < 4; ++mt) {
            const bf16x8 Ah = *reinterpret_cast<const bf16x8*>(&sA[bc][(mt * 3 + 0) * 512 + lane * 8]);
            const bf16x8 Am = *reinterpret_cast<const bf16x8*>(&sA[bc][(mt * 3 + 1) * 512 + lane * 8]);
            const bf16x8 Al = *reinterpret_cast<const bf16x8*>(&sA[bc][(mt * 3 + 2) * 512 + lane * 8]);
            accP[mt] = __builtin_amdgcn_mfma_f32_32x32x16_bf16(Ah, Bh, accP[mt], 0, 0, 0);
            accQ[mt] = __builtin_amdgcn_mfma_f32_32x32x16_bf16(Ah, Bm, accQ[mt], 0, 0, 0);
            accQ[mt] = __builtin_amdgcn_mfma_f32_32x32x16_bf16(Am, Bh, accQ[mt], 0, 0, 0);
            accQ[mt] = __builtin_amdgcn_mfma_f32_32x32x16_bf16(Ah, Bl, accQ[mt], 0, 0, 0);
            accQ[mt] = __builtin_amdgcn_mfma_f32_32x32x16_bf16(Al, Bh, accQ[mt], 0, 0, 0);
            accQ[mt] = __builtin_amdgcn_mfma_f32_32x32x16_bf16(Am, Bm, accQ[mt], 0, 0, 0);
        }
    }

    // epilogue: x[row][mt*32 + 8*(reg>>2) + 4*kg + (reg&3)] = P+Q; also 1/||x||
    float ss = 0.0f;
#pragma unroll
    for (int mt = 0; mt < 4; ++mt)
#pragma unroll
        for (int q = 0; q < 4; ++q) {
            float4 v;
            v.x = accP[mt][q * 4 + 0] + accQ[mt][q * 4 + 0];
            v.y = accP[mt][q * 4 + 1] + accQ[mt][q * 4 + 1];
            v.z = accP[mt][q * 4 + 2] + accQ[mt][q * 4 + 2];
            v.w = accP[mt][q * 4 + 3] + accQ[mt][q * 4 + 3];
            ss += v.x * v.x + v.y * v.y + v.z * v.z + v.w * v.w;
            *reinterpret_cast<float4*>(xw + (size_t)row * DEMB + mt * 32 + q * 8 + kg * 4) = v;
        }
    ss += __shfl_xor(ss, 32, 64);
    if (lane < 32) rnw[row] = 1.0f / sqrtf(ss);
}

// ---------------------------------------------------------------------------
// Kernel 2 (fallback): f32 VALU projection (r6 version, exact).
// ---------------------------------------------------------------------------
__global__ __launch_bounds__(256) void project_kernel(
        const float* __restrict__ inp, const float* __restrict__ proj,
        float* __restrict__ xw, float* __restrict__ rnw) {
    const int tid = threadIdx.x, tx = tid & 31, ty = tid >> 5;
    const int rowBase = blockIdx.x * 64;

    float acc1[8][4];
#pragma unroll
    for (int i = 0; i < 8; ++i)
#pragma unroll
        for (int j = 0; j < 4; ++j) acc1[i][j] = 0.0f;

    const float* inRow0 = inp + (size_t)(rowBase + ty) * DIN;
    const float* pjCol  = proj + tx * 4;

    float4 ivA[8], ivB[8], pjA[4], pjB[4];
    auto load_step = [&](float4 iv[8], float4 pj[4], int kk) {
#pragma unroll
        for (int j = 0; j < 4; ++j) pj[j] = ld4(pjCol + (size_t)(kk + j) * DEMB);
#pragma unroll
        for (int i = 0; i < 8; ++i) iv[i] = ld4(inRow0 + (size_t)(8 * i) * DIN + kk);
    };
    auto fma_step = [&](const float4 iv[8], const float4 pj[4]) {
#pragma unroll
        for (int i = 0; i < 8; ++i) {
            const float* ivp = reinterpret_cast<const float*>(&iv[i]);
#pragma unroll
            for (int j = 0; j < 4; ++j) {
                acc1[i][0] = fmaf(ivp[j], pj[j].x, acc1[i][0]);
                acc1[i][1] = fmaf(ivp[j], pj[j].y, acc1[i][1]);
                acc1[i][2] = fmaf(ivp[j], pj[j].z, acc1[i][2]);
                acc1[i][3] = fmaf(ivp[j], pj[j].w, acc1[i][3]);
            }
        }
    };
    load_step(ivA, pjA, 0);
#pragma unroll 1
    for (int k = 0; k < DIN; k += 8) {
        load_step(ivB, pjB, k + 4);
        fma_step(ivA, pjA);
        if (k + 8 < DIN) load_step(ivA, pjA, k + 8);
        fma_step(ivB, pjB);
    }
#pragma unroll
    for (int i = 0; i < 8; ++i) {
        const int r = rowBase + ty + 8 * i;
        float ss = acc1[i][0] * acc1[i][0] + acc1[i][1] * acc1[i][1] +
                   acc1[i][2] * acc1[i][2] + acc1[i][3] * acc1[i][3];
#pragma unroll
        for (int mm = 1; mm < 32; mm <<= 1) ss += __shfl_xor(ss, mm, 64);
        if (tx == 0) rnw[r] = 1.0f / sqrtf(ss);
        *reinterpret_cast<float4*>(xw + (size_t)r * DEMB + tx * 4) =
            make_float4(acc1[i][0], acc1[i][1], acc1[i][2], acc1[i][3]);
    }
}

// ---------------------------------------------------------------------------
// Kernel 3: similarity + margin argmax. Block = (256 rows, ONE codebook),
// 512 threads = 8 waves x 32 rows, grid 1024. Same 3-buffer LDS DMA pipeline
// as r6 (counted vmcnt, never 0 mid-loop; 1 barrier/tile); stage now
// 2 instrs/thread -> vmcnt(2). Uncertain rows appended for recheck kernel.
// ---------------------------------------------------------------------------
__global__ __launch_bounds__(512) void sim_kernel(
        const float* __restrict__ xw, const float* __restrict__ rnw,
        const unsigned short* __restrict__ cbA,
        int* __restrict__ out, int* __restrict__ unc_cnt,
        int* __restrict__ unc_list) {
    __shared__ __align__(16) short sA[3][8192];   // 3 x 16 KB tile buffers
    const int tid = threadIdx.x;
    const int lane = tid & 63, wv = tid >> 6;     // wv 0..7
    const int kg = lane >> 5;
    const int cbi = blockIdx.x & 3;
    const int rowBase = (blockIdx.x >> 2) * 256;
    const int row = rowBase + wv * 32 + (lane & 31);

    const short* gA = (const short*)cbA + (size_t)cbi * 16 * 8192;

    auto stage = [&](int buf, int t) {   // 16 KB tile, 2 DMA instrs/thread
        const short* g = gA + (size_t)t * 8192 + wv * 1024 + lane * 8;
        short* l = &sA[buf][wv * 1024];
#pragma unroll
        for (int c = 0; c < 2; ++c)
            gload_lds16(g + c * 512, l + c * 512);
    };

    stage(0, 0);
    stage(1, 1);

    // B-frag hoist: normalize + split hi/lo this lane's x row (once/wave).
    bf16x8 Bhi[8], Blo[8];
    {
        const float rn = rnw[row];
        const float* xr = xw + (size_t)row * DEMB;
#pragma unroll
        for (int kt = 0; kt < 8; ++kt) {
            const float4 f0 = ld4(xr + kt * 16 + kg * 8);
            const float4 f1 = ld4(xr + kt * 16 + kg * 8 + 4);
            const float xs[8] = {f0.x, f0.y, f0.z, f0.w, f1.x, f1.y, f1.z, f1.w};
            bf16x8 hv, lv;
#pragma unroll
            for (int e = 0; e < 8; ++e) {
                const float xn = xs[e] * rn;
                const unsigned short h = f2bf(xn);
                hv[e] = (short)h;
                lv[e] = (short)f2bf(xn - bf2f(h));
            }
            Bhi[kt] = hv; Blo[kt] = lv;
        }
    }

    float t1 = -INFINITY, t2 = -INFINITY; int i1 = 0;

#pragma unroll 1
    for (int ct = 0; ct < 16; ++ct) {
        if (ct < 15) asm volatile("s_waitcnt vmcnt(2)" ::: "memory");
        else         asm volatile("s_waitcnt vmcnt(0)" ::: "memory");
        __builtin_amdgcn_s_barrier();       // all waves' tile-ct DMA visible
        asm volatile("" ::: "memory");
        if (ct + 2 < 16) stage((ct + 2) % 3, ct + 2);

        f32x16 accA, accB1, accB2;
#pragma unroll
        for (int r = 0; r < 16; ++r) { accA[r] = 0.0f; accB1[r] = 0.0f; accB2[r] = 0.0f; }
        const short* pa = &sA[ct % 3][lane * 8];
#pragma unroll
        for (int kt = 0; kt < 8; ++kt) {
            const bf16x8 Ahi = *reinterpret_cast<const bf16x8*>(pa + kt * 1024);
            const bf16x8 Alo = *reinterpret_cast<const bf16x8*>(pa + kt * 1024 + 512);
            accA  = __builtin_amdgcn_mfma_f32_32x32x16_bf16(Ahi, Bhi[kt], accA,  0, 0, 0);
            accB1 = __builtin_amdgcn_mfma_f32_32x32x16_bf16(Ahi, Blo[kt], accB1, 0, 0, 0);
            accB2 = __builtin_amdgcn_mfma_f32_32x32x16_bf16(Alo, Bhi[kt], accB2, 0, 0, 0);
        }
#pragma unroll
        for (int r = 0; r < 16; ++r) {
            const float v = (accA[r] + accB1[r]) + accB2[r];
            const int gidx = ct * 32 + ((r & 3) + 8 * (r >> 2) + 4 * kg);
            t2 = fmaxf(t2, fminf(v, t1));
            if (v > t1) { t1 = v; i1 = gidx; }
        }
    }

    // merge kg halves (lane L <-> L^32: same x-row, disjoint codes)
    const float o1 = __shfl_xor(t1, 32, 64);
    const float o2 = __shfl_xor(t2, 32, 64);
    const int   oi = __shfl_xor(i1, 32, 64);
    const float m2 = fmaxf(fmaxf(t2, o2), fminf(t1, o1));
    if (o1 > t1 || (o1 == t1 && oi < i1)) { t1 = o1; i1 = oi; }
    const bool unc = (t1 - m2) < MARGIN;
    if (lane < 32 && !unc)
        out[(size_t)row * NCB + cbi] = i1;

    unsigned long long msk = __ballot(unc && lane < 32);
    if (lane == 0 && msk) {
        const int n = __popcll(msk);
        int base = atomicAdd(unc_cnt, n);
        while (msk) {
            const int r = __ffsll(msk) - 1; msk &= msk - 1;
            unc_list[base++] = ((rowBase + wv * 32 + r) << 2) | cbi;
        }
    }
}

// ---------------------------------------------------------------------------
// Kernel 4: exact recheck. Recomputes x EXACTLY (f32 inp@proj) per item --
// required because xw may be the MFMA x~ (1e-6-level noise would flip
// near-ties vs the np reference). Then exact f32 dots vs 512 codes; same
// scan order / tie rules as before (first-max).
// ---------------------------------------------------------------------------
__global__ __launch_bounds__(256) void recheck_kernel(
        const float* __restrict__ inp, const float* __restrict__ proj,
        const float* __restrict__ cbn,
        const int* __restrict__ unc_cnt, const int* __restrict__ unc_list,
        int* __restrict__ out) {
    __shared__ float sx[4][DEMB];
    const int lane = threadIdx.x & 63, wv = threadIdx.x >> 6;
    const int n = *unc_cnt;
    for (int it = blockIdx.x * 4 + wv; it < n; it += gridDim.x * 4) {
        const int item = unc_list[it];
        const int row = item >> 2, cbi = item & 3;
        // exact x: lane owns cols lane, lane+64
        {
            const float* ir = inp + (size_t)row * DIN;
            float a0 = 0.0f, a1 = 0.0f;
#pragma unroll 1
            for (int k = 0; k < DIN; k += 4) {
                const float4 iv = ld4(ir + k);
                const float* ivp = reinterpret_cast<const float*>(&iv);
#pragma unroll
                for (int j = 0; j < 4; ++j) {
                    a0 = fmaf(ivp[j], proj[(size_t)(k + j) * DEMB + lane],      a0);
                    a1 = fmaf(ivp[j], proj[(size_t)(k + j) * DEMB + lane + 64], a1);
                }
            }
            sx[wv][lane] = a0; sx[wv][lane + 64] = a1;   // same-wave LDS exchange
        }
        float best = -INFINITY; int bi = 0;
#pragma unroll 1
        for (int j = 0; j < 8; ++j) {
            const int c = lane + 64 * j;
            const float* cv = cbn + ((size_t)cbi * MCODES + c) * DEMB;
            float s0 = 0, s1 = 0, s2 = 0, s3 = 0;
#pragma unroll
            for (int k = 0; k < DEMB; k += 4) {
                const float4 xk = ld4(&sx[wv][k]);
                const float4 ck = ld4(cv + k);
                s0 = fmaf(xk.x, ck.x, s0); s1 = fmaf(xk.y, ck.y, s1);
                s2 = fmaf(xk.z, ck.z, s2); s3 = fmaf(xk.w, ck.w, s3);
            }
            const float s = (s0 + s1) + (s2 + s3);
            if (s > best) { best = s; bi = c; }
        }
#pragma unroll
        for (int mm = 1; mm < 64; mm <<= 1) {
            const float ov = __shfl_xor(best, mm, 64);
            const int   oc = __shfl_xor(bi, mm, 64);
            if (ov > best || (ov == best && oc < bi)) { best = ov; bi = oc; }
        }
        if (lane == 0) out[(size_t)row * NCB + cbi] = bi;
    }
}

// ---------------------------------------------------------------------------
// Fallback (ws too small): round-3 fused kernel (proven, 2 MB ws).
// ---------------------------------------------------------------------------
__global__ __launch_bounds__(256) void fused_quantize_kernel(
        const float* __restrict__ inp, const float* __restrict__ proj,
        const float* __restrict__ cbn, const unsigned short* __restrict__ cbA,
        int* __restrict__ out) {
    __shared__ float sX[128][132];
    __shared__ float sRn[128];
    const int tid = threadIdx.x;
    const int tx = tid & 31, ty = tid >> 5;
    const int rowBase = blockIdx.x * 128;

#pragma unroll 1
    for (int p = 0; p < 2; ++p) {
        float acc1[8][4];
#pragma unroll
        for (int i = 0; i < 8; ++i)
#pragma unroll
            for (int j = 0; j < 4; ++j) acc1[i][j] = 0.0f;
        const float* inRow0 = inp + (size_t)(rowBase + p * 64 + ty) * DIN;
        const float* pjCol  = proj + tx * 4;
        float4 ivA[8], ivB[8], pjA[4], pjB[4];
        auto load_step = [&](float4 iv[8], float4 pj[4], int kk) {
#pragma unroll
            for (int j = 0; j < 4; ++j) pj[j] = ld4(pjCol + (size_t)(kk + j) * DEMB);
#pragma unroll
            for (int i = 0; i < 8; ++i) iv[i] = ld4(inRow0 + (size_t)(8 * i) * DIN + kk);
        };
        auto fma_step = [&](const float4 iv[8], const float4 pj[4]) {
#pragma unroll
            for (int i = 0; i < 8; ++i) {
                const float* ivp = reinterpret_cast<const float*>(&iv[i]);
#pragma unroll
                for (int j = 0; j < 4; ++j) {
                    acc1[i][0] = fmaf(ivp[j], pj[j].x, acc1[i][0]);
                    acc1[i][1] = fmaf(ivp[j], pj[j].y, acc1[i][1]);
                    acc1[i][2] = fmaf(ivp[j], pj[j].z, acc1[i][2]);
                    acc1[i][3] = fmaf(ivp[j], pj[j].w, acc1[i][3]);
                }
            }
        };
        load_step(ivA, pjA, 0);
#pragma unroll 1
        for (int k = 0; k < DIN; k += 8) {
            load_step(ivB, pjB, k + 4);
            fma_step(ivA, pjA);
            if (k + 8 < DIN) load_step(ivA, pjA, k + 8);
            fma_step(ivB, pjB);
        }
#pragma unroll
        for (int i = 0; i < 8; ++i) {
            const int r = p * 64 + ty + 8 * i;
            float ss = acc1[i][0] * acc1[i][0] + acc1[i][1] * acc1[i][1] +
                       acc1[i][2] * acc1[i][2] + acc1[i][3] * acc1[i][3];
#pragma unroll
            for (int mm = 1; mm < 32; mm <<= 1) ss += __shfl_xor(ss, mm, 64);
            if (tx == 0) sRn[r] = 1.0f / sqrtf(ss);
            *reinterpret_cast<float4*>(&sX[r][tx * 4]) =
                make_float4(acc1[i][0], acc1[i][1], acc1[i][2], acc1[i][3]);
        }
    }
    __syncthreads();

    const int lane = tid & 63, wv = tid >> 6;
    const int kg = lane >> 5;
    const int rowL = wv * 32 + (lane & 31);
    bf16x8 Bhi[8], Blo[8];
    {
        const float rn = sRn[rowL];
#pragma unroll
        for (int kt = 0; kt < 8; ++kt) {
            const int k0 = kt * 16 + kg * 8;
            float4 f0 = ld4(&sX[rowL][k0]);
            float4 f1 = ld4(&sX[rowL][k0 + 4]);
            float xs[8] = {f0.x, f0.y, f0.z, f0.w, f1.x, f1.y, f1.z, f1.w};
            bf16x8 hv, lv;
#pragma unroll
            for (int e = 0; e < 8; ++e) {
                const float xn = xs[e] * rn;
                const unsigned short h = f2bf(xn);
                hv[e] = (short)h;
                lv[e] = (short)f2bf(xn - bf2f(h));
            }
            Bhi[kt] = hv; Blo[kt] = lv;
        }
    }
    float t1 = -INFINITY, t2 = -INFINITY; int i1 = 0;
    const short* pA = reinterpret_cast<const short*>(cbA) + (size_t)lane * 8;
#pragma unroll 1
    for (int ct = 0; ct < 64; ++ct) {
        if ((ct & 1) == 0) __syncthreads();
        const short* pct = pA + (size_t)ct * 8192;
        f32x16 accA, accB;
#pragma unroll
        for (int r = 0; r < 16; ++r) { accA[r] = 0.0f; accB[r] = 0.0f; }
#pragma unroll
        for (int kt = 0; kt < 8; ++kt) {
            const bf16x8 Ahi = *reinterpret_cast<const bf16x8*>(pct + kt * 1024);
            const bf16x8 Alo = *reinterpret_cast<const bf16x8*>(pct + kt * 1024 + 512);
            accA = __builtin_amdgcn_mfma_f32_32x32x16_bf16(Ahi, Bhi[kt], accA, 0, 0, 0);
            accB = __builtin_amdgcn_mfma_f32_32x32x16_bf16(Ahi, Blo[kt], accB, 0, 0, 0);
            accB = __builtin_amdgcn_mfma_f32_32x32x16_bf16(Alo, Bhi[kt], accB, 0, 0, 0);
        }
#pragma unroll
        for (int r = 0; r < 16; ++r) {
            const float v = accA[r] + accB[r];
            const int gidx = ct * 32 + ((r & 3) + 8 * (r >> 2) + 4 * kg);
            t2 = fmaxf(t2, fminf(v, t1));
            if (v > t1) { t1 = v; i1 = gidx; }
        }
        if ((ct & 15) == 15) {
            const int cbi = ct >> 4;
            const float o1 = __shfl_xor(t1, 32, 64);
            const float o2 = __shfl_xor(t2, 32, 64);
            const int   oi = __shfl_xor(i1, 32, 64);
            const float m2 = fmaxf(fmaxf(t2, o2), fminf(t1, o1));
            if (o1 > t1 || (o1 == t1 && oi < i1)) { t1 = o1; i1 = oi; }
            const bool unc = (t1 - m2) < MARGIN;
            if (lane < 32 && !unc)
                out[(size_t)(rowBase + rowL) * NCB + cbi] = i1 - cbi * MCODES;
            unsigned long long msk = __ballot(unc && lane < 32);
            while (msk) {
                const int r = __ffsll(msk) - 1; msk &= msk - 1;
                const int rl = wv * 32 + r;
                float best = -INFINITY; int bi = 0;
#pragma unroll 1
                for (int j = 0; j < 8; ++j) {
                    const int c = lane + 64 * j;
                    const float* cv = cbn + ((size_t)cbi * MCODES + c) * DEMB;
                    float s0 = 0, s1 = 0, s2 = 0, s3 = 0;
#pragma unroll
                    for (int k = 0; k < DEMB; k += 4) {
                        const float4 xk = ld4(&sX[rl][k]);
                        const float4 ck = ld4(cv + k);
                        s0 = fmaf(xk.x, ck.x, s0); s1 = fmaf(xk.y, ck.y, s1);
                        s2 = fmaf(xk.z, ck.z, s2); s3 = fmaf(xk.w, ck.w, s3);
                    }
                    const float s = (s0 + s1) + (s2 + s3);
                    if (s > best) { best = s; bi = c; }
                }
#pragma unroll
                for (int mm = 1; mm < 64; mm <<= 1) {
                    const float ov = __shfl_xor(best, mm, 64);
                    const int   oc = __shfl_xor(bi, mm, 64);
                    if (ov > best || (ov == best && oc < bi)) { best = ov; bi = oc; }
                }
                if (lane == 0) out[(size_t)(rowBase + rl) * NCB + cbi] = bi;
            }
            t1 = -INFINITY; t2 = -INFINITY; i1 = 0;
        }
    }
}

// ---------------------------------------------------------------------------
extern "C" void kernel_launch(void* const* d_in, const int* in_sizes, int n_in,
                              void* d_out, int out_size, void* d_ws, size_t ws_size,
                              hipStream_t stream) {
    const float* inp  = (const float*)d_in[0];   // [8,16,512,256]
    const float* proj = (const float*)d_in[1];   // [256,128]
    const float* cb   = (const float*)d_in[2];   // [4,512,128]
    int* out = (int*)d_out;                      // [8,16,512,4] int32

    char* ws = (char*)d_ws;
    float* cbn = (float*)ws;                                     // 1 MB
    unsigned short* cbA = (unsigned short*)(ws + (1 << 20));     // 1 MB
    float* rnw = (float*)(ws + (2 << 20));                       // 256 KB
    float* xw  = (float*)(ws + (2 << 20) + (1 << 18));           // 32 MB
    const size_t off_cnt = (size_t)(2 << 20) + (1 << 18) + ((size_t)32 << 20);
    int* unc_cnt  = (int*)(ws + off_cnt);                        // 4 B (pad 256)
    int* unc_list = (int*)(ws + off_cnt + 256);                  // 1 MB
    const size_t off_pjA = off_cnt + 256 + (1 << 20);
    unsigned short* pjA = (unsigned short*)(ws + off_pjA);       // 192 KB
    const size_t need_old = off_pjA;
    const size_t need_new = off_pjA + 192 * 1024;

    hipLaunchKernelGGL(prep_codebook, dim3(NCODE / 4), dim3(256), 0, stream,
                       cb, cbn, cbA);
    if (ws_size >= need_old) {
        hipMemsetAsync(unc_cnt, 0, 4, stream);
        if (ws_size >= need_new) {
            hipLaunchKernelGGL(prep_proj, dim3(16), dim3(256), 0, stream, proj, pjA);
            hipLaunchKernelGGL(project_mfma, dim3(512), dim3(256), 0, stream,
                               inp, pjA, xw, rnw);
        } else {
            hipLaunchKernelGGL(project_kernel, dim3(1024), dim3(256), 0, stream,
                               inp, proj, xw, rnw);
        }
        hipLaunchKernelGGL(sim_kernel, dim3(256 * NCB), dim3(512), 0, stream,
                           xw, rnw, cbA, out, unc_cnt, unc_list);
        hipLaunchKernelGGL(recheck_kernel, dim3(512), dim3(256), 0, stream,
                           inp, proj, cbn, unc_cnt, unc_list, out);
    } else {
        hipLaunchKernelGGL(fused_quantize_kernel, dim3(512), dim3(256), 0, stream,
                           inp, proj, cbn, cbA, out);
    }
}